// Round 7
// baseline (596.837 us; speedup 1.0000x reference)
//
#include <hip/hip_runtime.h>

#define NEG_SLOPE 0.2f
#define LOG2E 1.44269504088896340736f

typedef unsigned short ushort_t;
typedef unsigned int uint_t;
typedef __attribute__((ext_vector_type(8))) short bf16x8;   // 8 bf16 in 4 VGPRs
typedef __attribute__((ext_vector_type(4))) float f32x4;

__device__ inline float bf2f(ushort_t u) { union { uint_t i; float f; } v; v.i = ((uint_t)u) << 16; return v.f; }
__device__ inline ushort_t f2bf(float f) {
    union { float f; uint_t u; } v; v.f = f;
    uint_t r = v.u + 0x7fffu + ((v.u >> 16) & 1u);
    return (ushort_t)(r >> 16);
}
__device__ inline float2 up2(uint_t w) { return make_float2(bf2f((ushort_t)(w & 0xFFFFu)), bf2f((ushort_t)(w >> 16))); }
// dtype-flexible loads (bf=1: buffer holds bf16; bf=0: fp32)
__device__ inline float ld_f(const void* p, size_t i, int bf) { return bf ? bf2f(((const ushort_t*)p)[i]) : ((const float*)p)[i]; }
__device__ inline ushort_t ld_b(const void* p, size_t i, int bf) { return bf ? ((const ushort_t*)p)[i] : f2bf(((const float*)p)[i]); }
// edge fetch with int64/int32 handling; self-loops appended at e >= E_in
__device__ inline void edge_sd(const int* __restrict__ ei, int e, int E_in, int i64, int& src, int& dst) {
    if (e < E_in) {
        if (i64) { src = ei[2 * (size_t)e]; dst = ei[2 * ((size_t)E_in + e)]; }
        else     { src = ei[e];             dst = ei[(size_t)E_in + e]; }
    } else { src = dst = e - E_in; }
}
// att-folded leaky dot contribution: att*leaky(m) == (0.6*att)*m + (0.4*att)*|m| (log2e folded)
__device__ inline float dot2(float2 m, float2 a6, float2 a4, float e) {
    e = fmaf(a6.x, m.x, e); e = fmaf(a4.x, __builtin_fabsf(m.x), e);
    e = fmaf(a6.y, m.y, e); e = fmaf(a4.y, __builtin_fabsf(m.y), e);
    return e;
}

// ---------------- dtype detection ----------------
__global__ void k_detect(const uint_t* __restrict__ xw, const int* __restrict__ ei, int* flags) {
    __shared__ int cnt;
    if (threadIdx.x == 0) cnt = 0;
    __syncthreads();
    uint_t w = xw[threadIdx.x];
    int eb = (int)((w >> 7) & 0xFFu);
    if (eb >= 113 && eb <= 142) atomicAdd(&cnt, 1);
    __syncthreads();
    if (threadIdx.x == 0) {
        flags[0] = (cnt > 128) ? 1 : 0;
        int z = 0;
        #pragma unroll
        for (int i = 1; i < 16; i += 2) z += (ei[i] == 0) ? 1 : 0;
        flags[1] = (z == 8) ? 1 : 0;
    }
}

// ------ fused front-end: zero deg | cvt x->bf16 | build WT (transposed bf16) | small fp32 params ------
__global__ __launch_bounds__(256) void k_prep(const void* __restrict__ x, const void* Wl1, const void* Wr1,
                      const void* att1, const void* b1, const void* Wl2, const void* Wr2,
                      const void* att2, const void* b2, const void* Wo, const void* bo,
                      int* deg, ushort_t* xb,
                      ushort_t* WTl1, ushort_t* WTr1, ushort_t* WTl2, ushort_t* WTr2,
                      float* att1f, float* b1f, float* att2f, float* b2f, float* Wof, float* bof,
                      int N, int sW1, int sW2, int satt1, int sb1, int satt2, int sb2, int sWo, int sbo,
                      const int* flags) {
    int bf = flags[0];
    long idx = (long)blockIdx.x * 256 + threadIdx.x;
    long r = idx;
    if (r < N) { deg[r] = 0; return; }                       r -= N;
    long nx = (long)N * 128;
    if (r < nx) { xb[r] = ld_b(x, r, bf); return; }          r -= nx;
    if (r < sW1) { int n = r >> 7, k = r & 127; WTl1[r] = ld_b(Wl1, (size_t)k * 128 + n, bf); return; } r -= sW1;
    if (r < sW1) { int n = r >> 7, k = r & 127; WTr1[r] = ld_b(Wr1, (size_t)k * 128 + n, bf); return; } r -= sW1;
    if (r < sW2) { int n = r >> 7, k = r & 127; WTl2[r] = ld_b(Wl2, (size_t)k * 512 + n, bf); return; } r -= sW2;
    if (r < sW2) { int n = r >> 7, k = r & 127; WTr2[r] = ld_b(Wr2, (size_t)k * 512 + n, bf); return; } r -= sW2;
    if (r < satt1) { att1f[r] = ld_f(att1, r, bf); return; } r -= satt1;
    if (r < sb1)   { b1f[r]   = ld_f(b1, r, bf);   return; } r -= sb1;
    if (r < satt2) { att2f[r] = ld_f(att2, r, bf); return; } r -= satt2;
    if (r < sb2)   { b2f[r]   = ld_f(b2, r, bf);   return; } r -= sb2;
    if (r < sWo)   { Wof[r]   = ld_f(Wo, r, bf);   return; } r -= sWo;
    if (r < sbo)   { bof[r]   = ld_f(bo, r, bf);   return; }
}

// ---------------- CSR build over dst ----------------
__global__ void k_count(const int* __restrict__ ei, int E_in, int Etot, const int* flags, int* deg) {
    int e = blockIdx.x * blockDim.x + threadIdx.x;
    if (e >= Etot) return;
    int dst;
    if (e < E_in) dst = flags[1] ? ei[2 * ((size_t)E_in + e)] : ei[(size_t)E_in + e];
    else          dst = e - E_in;
    atomicAdd(&deg[dst], 1);
}

// -------- hierarchical exclusive scan --------
__global__ __launch_bounds__(256) void k_scanA(const int* __restrict__ deg, int* offs, int* bsum, int n) {
    __shared__ int sh[256];
    int t = threadIdx.x;
    int i = blockIdx.x * 256 + t;
    int v = (i < n) ? deg[i] : 0;
    sh[t] = v; __syncthreads();
    #pragma unroll
    for (int off = 1; off < 256; off <<= 1) {
        int u = (t >= off) ? sh[t - off] : 0;
        __syncthreads();
        sh[t] += u; __syncthreads();
    }
    if (i < n) offs[i] = sh[t] - v;
    if (t == 255) bsum[blockIdx.x] = sh[255];
}

__global__ __launch_bounds__(256) void k_scanB(int* bsum, int* offs, int nb, int n) {
    __shared__ int sh[256];
    int t = threadIdx.x;
    int v = (t < nb) ? bsum[t] : 0;
    sh[t] = v; __syncthreads();
    #pragma unroll
    for (int off = 1; off < 256; off <<= 1) {
        int u = (t >= off) ? sh[t - off] : 0;
        __syncthreads();
        sh[t] += u; __syncthreads();
    }
    if (t < nb) bsum[t] = sh[t] - v;
    if (t == 255) offs[n] = sh[255];
}

__global__ __launch_bounds__(256) void k_scanC(int* offs, int* cursor, const int* __restrict__ bsum, int n) {
    int i = blockIdx.x * 256 + threadIdx.x;
    if (i >= n) return;
    int o = offs[i] + bsum[blockIdx.x];
    offs[i] = o; cursor[i] = o;
}

__global__ void k_fill(const int* __restrict__ ei, int E_in, int Etot, const int* flags,
                       int* cursor, int* s_src) {
    int e = blockIdx.x * blockDim.x + threadIdx.x;
    if (e >= Etot) return;
    int src, dst; edge_sd(ei, e, E_in, flags[1], src, dst);
    int p = atomicAdd(&cursor[dst], 1);
    s_src[p] = src;
}

// ---- fused dual MFMA GEMM: Yl/Yr[M,NOUT] = X[M,128] @ {WTl,WTr}; A-frags loaded once ----
template <int NOUT>
__global__ __launch_bounds__(256) void k_gemm2(const ushort_t* __restrict__ X,
                                               const ushort_t* __restrict__ WTl,
                                               const ushort_t* __restrict__ WTr,
                                               ushort_t* __restrict__ Yl,
                                               ushort_t* __restrict__ Yr, int M) {
    const int lane = threadIdx.x & 63, wid = threadIdx.x >> 6;
    int rt = blockIdx.x * 4 + wid;
    if (rt >= (M >> 4)) return;
    const int quad = lane >> 4, lo = lane & 15;

    const ushort_t* xrow = X + (size_t)(rt * 16 + lo) * 128 + quad * 8;
    bf16x8 afr[4];
    #pragma unroll
    for (int kc = 0; kc < 4; kc++) afr[kc] = *(const bf16x8*)(xrow + kc * 32);

    #pragma unroll
    for (int g = 0; g < NOUT / 64; g++) {
        #pragma unroll
        for (int side = 0; side < 2; side++) {
            const ushort_t* WT = side ? WTr : WTl;
            ushort_t*       Y  = side ? Yr  : Yl;
            f32x4 acc[4];
            #pragma unroll
            for (int nt = 0; nt < 4; nt++) acc[nt] = (f32x4){0.f, 0.f, 0.f, 0.f};
            #pragma unroll
            for (int nt = 0; nt < 4; nt++) {
                const ushort_t* wrow = WT + (size_t)(g * 64 + nt * 16 + lo) * 128 + quad * 8;
                #pragma unroll
                for (int kc = 0; kc < 4; kc++) {
                    bf16x8 b = *(const bf16x8*)(wrow + kc * 32);
                    acc[nt] = __builtin_amdgcn_mfma_f32_16x16x32_bf16(afr[kc], b, acc[nt], 0, 0, 0);
                }
            }
            // C/D: col = lane&15, row = quad*4 + reg  [m89-verified]
            #pragma unroll
            for (int nt = 0; nt < 4; nt++) {
                int col = g * 64 + nt * 16 + lo;
                #pragma unroll
                for (int ri = 0; ri < 4; ri++) {
                    int row = rt * 16 + quad * 4 + ri;
                    Y[(size_t)row * NOUT + col] = f2bf(acc[nt][ri]);
                }
            }
        }
    }
}

// ======== layer 1 FUSED: slot-parallel exp-sum gather -> h1 (bf16), unroll-2 ========
// wave per node. 4 slots x 16 lanes; lane covers 8 ch; head = (lane&15)>>2.
__global__ __launch_bounds__(256) void k_l1(const ushort_t* __restrict__ xl,
                                            const ushort_t* __restrict__ xr,
                                            const int* __restrict__ offs,
                                            const int* __restrict__ s_src,
                                            const float* __restrict__ att,
                                            const float* __restrict__ b1,
                                            int n, ushort_t* __restrict__ h1) {
    int lane = threadIdx.x & 63, wid = threadIdx.x >> 6;
    int node = blockIdx.x * 4 + wid;
    if (node >= n) return;
    int slot = lane >> 4, sub = lane & 15;
    int chb = sub * 8;

    uint4 xw = *(const uint4*)(xr + (size_t)node * 128 + chb);
    float2 xv[4] = {up2(xw.x), up2(xw.y), up2(xw.z), up2(xw.w)};
    float2 a6[4], a4[4];
    #pragma unroll
    for (int j = 0; j < 4; j++) {
        float2 a = make_float2(att[chb + 2 * j], att[chb + 2 * j + 1]);
        a6[j] = make_float2(0.6f * LOG2E * a.x, 0.6f * LOG2E * a.y);
        a4[j] = make_float2(0.4f * LOG2E * a.x, 0.4f * LOG2E * a.y);
    }

    int o0 = offs[node], o1 = offs[node + 1];
    float s = 0.f;
    float2 acc[4] = {{0.f,0.f},{0.f,0.f},{0.f,0.f},{0.f,0.f}};

    int i = o0 + slot;
    uint4 w0, w1;
    if (i < o1)     w0 = *(const uint4*)(xl + (size_t)s_src[i] * 128 + chb);
    if (i + 4 < o1) w1 = *(const uint4*)(xl + (size_t)s_src[i + 4] * 128 + chb);
    while (i + 4 < o1) {
        uint4 wa = w0, wb = w1;
        if (i + 8 < o1)  w0 = *(const uint4*)(xl + (size_t)s_src[i + 8] * 128 + chb);
        if (i + 12 < o1) w1 = *(const uint4*)(xl + (size_t)s_src[i + 12] * 128 + chb);
        float2 va[4] = {up2(wa.x), up2(wa.y), up2(wa.z), up2(wa.w)};
        float2 vb[4] = {up2(wb.x), up2(wb.y), up2(wb.z), up2(wb.w)};
        float ea = 0.f, eb = 0.f;
        #pragma unroll
        for (int j = 0; j < 4; j++) {
            ea = dot2(make_float2(va[j].x + xv[j].x, va[j].y + xv[j].y), a6[j], a4[j], ea);
            eb = dot2(make_float2(vb[j].x + xv[j].x, vb[j].y + xv[j].y), a6[j], a4[j], eb);
        }
        ea += __shfl_xor(ea, 1, 64); eb += __shfl_xor(eb, 1, 64);
        ea += __shfl_xor(ea, 2, 64); eb += __shfl_xor(eb, 2, 64);
        float pa = __builtin_amdgcn_exp2f(fminf(ea, 115.f));
        float pb = __builtin_amdgcn_exp2f(fminf(eb, 115.f));
        s += pa + pb;
        #pragma unroll
        for (int j = 0; j < 4; j++) {
            acc[j].x = fmaf(pa, va[j].x, acc[j].x); acc[j].y = fmaf(pa, va[j].y, acc[j].y);
            acc[j].x = fmaf(pb, vb[j].x, acc[j].x); acc[j].y = fmaf(pb, vb[j].y, acc[j].y);
        }
        i += 8;
    }
    if (i < o1) {
        float2 va[4] = {up2(w0.x), up2(w0.y), up2(w0.z), up2(w0.w)};
        float e = 0.f;
        #pragma unroll
        for (int j = 0; j < 4; j++)
            e = dot2(make_float2(va[j].x + xv[j].x, va[j].y + xv[j].y), a6[j], a4[j], e);
        e += __shfl_xor(e, 1, 64);
        e += __shfl_xor(e, 2, 64);
        float p = __builtin_amdgcn_exp2f(fminf(e, 115.f));
        s += p;
        #pragma unroll
        for (int j = 0; j < 4; j++) {
            acc[j].x = fmaf(p, va[j].x, acc[j].x); acc[j].y = fmaf(p, va[j].y, acc[j].y);
        }
    }
    // merge the 4 slots: plain butterfly adds
    #pragma unroll
    for (int off = 16; off <= 32; off <<= 1) {
        s += __shfl_xor(s, off, 64);
        #pragma unroll
        for (int j = 0; j < 4; j++) {
            acc[j].x += __shfl_xor(acc[j].x, off, 64);
            acc[j].y += __shfl_xor(acc[j].y, off, 64);
        }
    }
    if (slot == 0) {
        float inv = 1.f / s;
        uint_t pk[4];
        #pragma unroll
        for (int j = 0; j < 4; j++) {
            float r0 = fmaxf(fmaf(acc[j].x, inv, b1[chb + 2 * j]),     0.f);
            float r1 = fmaxf(fmaf(acc[j].y, inv, b1[chb + 2 * j + 1]), 0.f);
            pk[j] = (uint_t)f2bf(r0) | ((uint_t)f2bf(r1) << 16);
        }
        *(uint4*)(h1 + (size_t)node * 128 + chb) = make_uint4(pk[0], pk[1], pk[2], pk[3]);
    }
}

// ======== layer 2 FUSED: slot-parallel exp-sum + mean-heads + b2 + decoder, unroll-2 ========
// block per node; wave = head. 4 slots x 16 lanes x 8 ch.
__global__ __launch_bounds__(256) void k_l2(const ushort_t* __restrict__ xl,
                                            const ushort_t* __restrict__ xr,
                                            const int* __restrict__ offs,
                                            const int* __restrict__ s_src,
                                            const float* __restrict__ att,
                                            const float* __restrict__ b2,
                                            const float* __restrict__ Wo,
                                            const float* __restrict__ bo,
                                            int n, const int* flags, void* dout) {
    __shared__ float part[4][128];
    __shared__ float hbuf[128];
    int node = blockIdx.x;
    int h = threadIdx.x >> 6, lane = threadIdx.x & 63;
    int slot = lane >> 4, sub = lane & 15;
    int chb = sub * 8;
    size_t choff = (size_t)h * 128 + chb;

    uint4 xw = *(const uint4*)(xr + (size_t)node * 512 + choff);
    float2 xv[4] = {up2(xw.x), up2(xw.y), up2(xw.z), up2(xw.w)};
    float2 a6[4], a4[4];
    #pragma unroll
    for (int j = 0; j < 4; j++) {
        float2 a = make_float2(att[choff + 2 * j], att[choff + 2 * j + 1]);
        a6[j] = make_float2(0.6f * LOG2E * a.x, 0.6f * LOG2E * a.y);
        a4[j] = make_float2(0.4f * LOG2E * a.x, 0.4f * LOG2E * a.y);
    }

    int o0 = offs[node], o1 = offs[node + 1];
    float s = 0.f;
    float2 acc[4] = {{0.f,0.f},{0.f,0.f},{0.f,0.f},{0.f,0.f}};

    int i = o0 + slot;
    uint4 w0, w1;
    if (i < o1)     w0 = *(const uint4*)(xl + (size_t)s_src[i] * 512 + choff);
    if (i + 4 < o1) w1 = *(const uint4*)(xl + (size_t)s_src[i + 4] * 512 + choff);
    while (i + 4 < o1) {
        uint4 wa = w0, wb = w1;
        if (i + 8 < o1)  w0 = *(const uint4*)(xl + (size_t)s_src[i + 8] * 512 + choff);
        if (i + 12 < o1) w1 = *(const uint4*)(xl + (size_t)s_src[i + 12] * 512 + choff);
        float2 va[4] = {up2(wa.x), up2(wa.y), up2(wa.z), up2(wa.w)};
        float2 vb[4] = {up2(wb.x), up2(wb.y), up2(wb.z), up2(wb.w)};
        float ea = 0.f, eb = 0.f;
        #pragma unroll
        for (int j = 0; j < 4; j++) {
            ea = dot2(make_float2(va[j].x + xv[j].x, va[j].y + xv[j].y), a6[j], a4[j], ea);
            eb = dot2(make_float2(vb[j].x + xv[j].x, vb[j].y + xv[j].y), a6[j], a4[j], eb);
        }
        #pragma unroll
        for (int o = 1; o < 16; o <<= 1) { ea += __shfl_xor(ea, o, 64); eb += __shfl_xor(eb, o, 64); }
        float pa = __builtin_amdgcn_exp2f(fminf(ea, 115.f));
        float pb = __builtin_amdgcn_exp2f(fminf(eb, 115.f));
        s += pa + pb;
        #pragma unroll
        for (int j = 0; j < 4; j++) {
            acc[j].x = fmaf(pa, va[j].x, acc[j].x); acc[j].y = fmaf(pa, va[j].y, acc[j].y);
            acc[j].x = fmaf(pb, vb[j].x, acc[j].x); acc[j].y = fmaf(pb, vb[j].y, acc[j].y);
        }
        i += 8;
    }
    if (i < o1) {
        float2 va[4] = {up2(w0.x), up2(w0.y), up2(w0.z), up2(w0.w)};
        float e = 0.f;
        #pragma unroll
        for (int j = 0; j < 4; j++)
            e = dot2(make_float2(va[j].x + xv[j].x, va[j].y + xv[j].y), a6[j], a4[j], e);
        #pragma unroll
        for (int o = 1; o < 16; o <<= 1) e += __shfl_xor(e, o, 64);
        float p = __builtin_amdgcn_exp2f(fminf(e, 115.f));
        s += p;
        #pragma unroll
        for (int j = 0; j < 4; j++) {
            acc[j].x = fmaf(p, va[j].x, acc[j].x); acc[j].y = fmaf(p, va[j].y, acc[j].y);
        }
    }
    // merge slots: plain butterfly adds
    #pragma unroll
    for (int off = 16; off <= 32; off <<= 1) {
        s += __shfl_xor(s, off, 64);
        #pragma unroll
        for (int j = 0; j < 4; j++) {
            acc[j].x += __shfl_xor(acc[j].x, off, 64);
            acc[j].y += __shfl_xor(acc[j].y, off, 64);
        }
    }
    if (slot == 0) {
        float inv = 1.f / s;
        #pragma unroll
        for (int j = 0; j < 4; j++) {
            part[h][chb + 2 * j]     = acc[j].x * inv;
            part[h][chb + 2 * j + 1] = acc[j].y * inv;
        }
    }
    __syncthreads();
    int t = threadIdx.x;
    int bf = flags[0];
    if (t < 128) {
        float hm = 0.25f * (part[0][t] + part[1][t] + part[2][t] + part[3][t]) + b2[t];
        hbuf[t] = hm;
        size_t oidx = (size_t)n * 2 + (size_t)node * 128 + t;
        if (bf) ((ushort_t*)dout)[oidx] = f2bf(hm);
        else    ((float*)dout)[oidx]    = hm;
    }
    __syncthreads();
    if (h < 2) {  // decoder
        float v = hbuf[lane] * Wo[lane * 2 + h] + hbuf[lane + 64] * Wo[(lane + 64) * 2 + h];
        #pragma unroll
        for (int o = 32; o > 0; o >>= 1) v += __shfl_xor(v, o, 64);
        if (lane == 0) {
            float r = v + bo[h];
            size_t oidx = (size_t)node * 2 + h;
            if (bf) ((ushort_t*)dout)[oidx] = f2bf(r);
            else    ((float*)dout)[oidx]    = r;
        }
    }
}

extern "C" void kernel_launch(void* const* d_in, const int* in_sizes, int n_in,
                              void* d_out, int out_size, void* d_ws, size_t ws_size,
                              hipStream_t stream) {
    const void* x    = d_in[0];
    const int*  ei   = (const int*)d_in[1];
    const void* Wl1  = d_in[2];
    const void* Wr1  = d_in[3];
    const void* att1 = d_in[4];
    const void* b1   = d_in[5];
    const void* Wl2  = d_in[6];
    const void* Wr2  = d_in[7];
    const void* att2 = d_in[8];
    const void* b2   = d_in[9];
    const void* Wo   = d_in[10];
    const void* bo   = d_in[11];

    const int N    = in_sizes[0] / 128;   // 50000
    const int E_in = in_sizes[1] / 2;     // 800000
    const int Etot = E_in + N;

    const int sW1 = in_sizes[2], sW2 = in_sizes[6];
    const int satt1 = in_sizes[4], sb1 = in_sizes[5];
    const int satt2 = in_sizes[8], sb2 = in_sizes[9];
    const int sWo = in_sizes[10], sbo = in_sizes[11];

    char* w = (char*)d_ws;
    size_t off = 0;
    auto take = [&](size_t bytes) -> void* {
        void* p = w + off;
        off += (bytes + 255) & ~(size_t)255;
        return p;
    };
    int*      flags  = (int*)take(256);
    ushort_t* xb     = (ushort_t*)take((size_t)N * 128 * sizeof(ushort_t));
    ushort_t* WTl1   = (ushort_t*)take((size_t)sW1 * 2);
    ushort_t* WTr1   = (ushort_t*)take((size_t)sW1 * 2);
    ushort_t* WTl2   = (ushort_t*)take((size_t)sW2 * 2);
    ushort_t* WTr2   = (ushort_t*)take((size_t)sW2 * 2);
    float*    att1f  = (float*)take((size_t)satt1 * 4);
    float*    b1f    = (float*)take((size_t)sb1 * 4);
    float*    att2f  = (float*)take((size_t)satt2 * 4);
    float*    b2f    = (float*)take((size_t)sb2 * 4);
    float*    Wof    = (float*)take((size_t)sWo * 4);
    float*    bof    = (float*)take((size_t)sbo * 4);
    int*      deg    = (int*)take((size_t)N * sizeof(int));
    int*      offs   = (int*)take((size_t)(N + 1) * sizeof(int));
    int*      cursor = (int*)take((size_t)(N + 1) * sizeof(int));
    int*      bsum   = (int*)take(1024);
    int*      s_src  = (int*)take((size_t)Etot * sizeof(int));
    ushort_t* h1     = (ushort_t*)take((size_t)N * 128 * sizeof(ushort_t));
    ushort_t* xl1b   = (ushort_t*)take((size_t)N * 128 * sizeof(ushort_t));
    ushort_t* xr1b   = (ushort_t*)take((size_t)N * 128 * sizeof(ushort_t));
    ushort_t* xl2b   = (ushort_t*)take((size_t)N * 512 * sizeof(ushort_t));
    ushort_t* xr2b   = (ushort_t*)take((size_t)N * 512 * sizeof(ushort_t));

    dim3 b256(256);
    const int nb = (N + 255) / 256;       // 196 scan blocks

    k_detect<<<1, b256, 0, stream>>>((const uint_t*)x, ei, flags);

    long prep_total = (long)N + (long)N * 128 + 2L * sW1 + 2L * sW2
                    + satt1 + sb1 + satt2 + sb2 + sWo + sbo;
    int prep_blocks = (int)((prep_total + 255) / 256);
    k_prep<<<prep_blocks, b256, 0, stream>>>(x, Wl1, Wr1, att1, b1, Wl2, Wr2, att2, b2, Wo, bo,
                                             deg, xb, WTl1, WTr1, WTl2, WTr2,
                                             att1f, b1f, att2f, b2f, Wof, bof,
                                             N, sW1, sW2, satt1, sb1, satt2, sb2, sWo, sbo, flags);

    k_count<<<(Etot + 255) / 256, b256, 0, stream>>>(ei, E_in, Etot, flags, deg);
    k_scanA<<<nb, b256, 0, stream>>>(deg, offs, bsum, N);
    k_scanB<<<1, b256, 0, stream>>>(bsum, offs, nb, N);
    k_scanC<<<nb, b256, 0, stream>>>(offs, cursor, bsum, N);
    k_fill<<<(Etot + 255) / 256, b256, 0, stream>>>(ei, E_in, Etot, flags, cursor, s_src);

    dim3 gg((N / 16 + 3) / 4);
    k_gemm2<128><<<gg, b256, 0, stream>>>(xb, WTl1, WTr1, xl1b, xr1b, N);
    k_l1<<<(N + 3) / 4, b256, 0, stream>>>(xl1b, xr1b, offs, s_src, att1f, b1f, N, h1);

    k_gemm2<512><<<gg, b256, 0, stream>>>(h1, WTl2, WTr2, xl2b, xr2b, N);

    k_l2<<<N, b256, 0, stream>>>(xl2b, xr2b, offs, s_src, att2f, b2f, Wof, bof, N, flags, d_out);
}

// Round 9
// 462.965 us; speedup vs baseline: 1.2892x; 1.2892x over previous
//
#include <hip/hip_runtime.h>

#define NEG_SLOPE 0.2f
#define LOG2E 1.44269504088896340736f

typedef unsigned short ushort_t;
typedef unsigned int uint_t;
typedef __attribute__((ext_vector_type(8))) short bf16x8;   // 8 bf16 in 4 VGPRs
typedef __attribute__((ext_vector_type(4))) float f32x4;

__device__ inline float bf2f(ushort_t u) { union { uint_t i; float f; } v; v.i = ((uint_t)u) << 16; return v.f; }
__device__ inline ushort_t f2bf(float f) {
    union { float f; uint_t u; } v; v.f = f;
    uint_t r = v.u + 0x7fffu + ((v.u >> 16) & 1u);
    return (ushort_t)(r >> 16);
}
__device__ inline float2 up2(uint_t w) { return make_float2(bf2f((ushort_t)(w & 0xFFFFu)), bf2f((ushort_t)(w >> 16))); }
// dtype-flexible loads (bf=1: buffer holds bf16; bf=0: fp32)
__device__ inline float ld_f(const void* p, size_t i, int bf) { return bf ? bf2f(((const ushort_t*)p)[i]) : ((const float*)p)[i]; }
__device__ inline ushort_t ld_b(const void* p, size_t i, int bf) { return bf ? ((const ushort_t*)p)[i] : f2bf(((const float*)p)[i]); }
// edge fetch with int64/int32 handling; self-loops appended at e >= E_in
__device__ inline void edge_sd(const int* __restrict__ ei, int e, int E_in, int i64, int& src, int& dst) {
    if (e < E_in) {
        if (i64) { src = ei[2 * (size_t)e]; dst = ei[2 * ((size_t)E_in + e)]; }
        else     { src = ei[e];             dst = ei[(size_t)E_in + e]; }
    } else { src = dst = e - E_in; }
}
// att-folded leaky dot: att*leaky(m)*log2e == a6*m + a4*|m|  (a6/a4 pre-scaled)
__device__ inline float dot2(float2 m, float2 a6, float2 a4, float e) {
    e = fmaf(a6.x, m.x, e); e = fmaf(a4.x, __builtin_fabsf(m.x), e);
    e = fmaf(a6.y, m.y, e); e = fmaf(a4.y, __builtin_fabsf(m.y), e);
    return e;
}

// ---------------- dtype detection ----------------
__global__ void k_detect(const uint_t* __restrict__ xw, const int* __restrict__ ei, int* flags) {
    __shared__ int cnt;
    if (threadIdx.x == 0) cnt = 0;
    __syncthreads();
    uint_t w = xw[threadIdx.x];
    int eb = (int)((w >> 7) & 0xFFu);
    if (eb >= 113 && eb <= 142) atomicAdd(&cnt, 1);
    __syncthreads();
    if (threadIdx.x == 0) {
        flags[0] = (cnt > 128) ? 1 : 0;
        int z = 0;
        #pragma unroll
        for (int i = 1; i < 16; i += 2) z += (ei[i] == 0) ? 1 : 0;
        flags[1] = (z == 8) ? 1 : 0;
    }
}

// ------ fused front-end: degree count | cvt x->bf16 | build WT | small fp32 params ------
// deg must be pre-zeroed (hipMemsetAsync before this kernel).
__global__ __launch_bounds__(256) void k_prep(const void* __restrict__ x, const void* Wl1, const void* Wr1,
                      const void* att1, const void* b1, const void* Wl2, const void* Wr2,
                      const void* att2, const void* b2, const void* Wo, const void* bo,
                      const int* __restrict__ ei, int E_in, int Etot, int* deg, ushort_t* xb,
                      ushort_t* WTl1, ushort_t* WTr1, ushort_t* WTl2, ushort_t* WTr2,
                      float* att1f, float* b1f, float* att2f, float* b2f, float* Wof, float* bof,
                      int N, int sW1, int sW2, int satt1, int sb1, int satt2, int sb2, int sWo, int sbo,
                      const int* flags) {
    int bf = flags[0];
    long r = (long)blockIdx.x * 256 + threadIdx.x;
    if (r < Etot) {   // degree count
        int e = (int)r, dst;
        if (e < E_in) dst = flags[1] ? ei[2 * ((size_t)E_in + e)] : ei[(size_t)E_in + e];
        else          dst = e - E_in;
        atomicAdd(&deg[dst], 1);
        return;
    }
    r -= Etot;
    long nx = (long)N * 128;
    if (r < nx) { xb[r] = ld_b(x, r, bf); return; }          r -= nx;
    if (r < sW1) { int n = r >> 7, k = r & 127; WTl1[r] = ld_b(Wl1, (size_t)k * 128 + n, bf); return; } r -= sW1;
    if (r < sW1) { int n = r >> 7, k = r & 127; WTr1[r] = ld_b(Wr1, (size_t)k * 128 + n, bf); return; } r -= sW1;
    if (r < sW2) { int n = r >> 7, k = r & 127; WTl2[r] = ld_b(Wl2, (size_t)k * 512 + n, bf); return; } r -= sW2;
    if (r < sW2) { int n = r >> 7, k = r & 127; WTr2[r] = ld_b(Wr2, (size_t)k * 512 + n, bf); return; } r -= sW2;
    if (r < satt1) { att1f[r] = ld_f(att1, r, bf); return; } r -= satt1;
    if (r < sb1)   { b1f[r]   = ld_f(b1, r, bf);   return; } r -= sb1;
    if (r < satt2) { att2f[r] = ld_f(att2, r, bf); return; } r -= satt2;
    if (r < sb2)   { b2f[r]   = ld_f(b2, r, bf);   return; } r -= sb2;
    if (r < sWo)   { Wof[r]   = ld_f(Wo, r, bf);   return; } r -= sWo;
    if (r < sbo)   { bof[r]   = ld_f(bo, r, bf);   return; }
}

// -------- hierarchical exclusive scan: A (block scan) -> BC (re-scan sums + add) --------
__global__ __launch_bounds__(256) void k_scanA(const int* __restrict__ deg, int* offs, int* bsum, int n) {
    __shared__ int sh[256];
    int t = threadIdx.x;
    int i = blockIdx.x * 256 + t;
    int v = (i < n) ? deg[i] : 0;
    sh[t] = v; __syncthreads();
    #pragma unroll
    for (int off = 1; off < 256; off <<= 1) {
        int u = (t >= off) ? sh[t - off] : 0;
        __syncthreads();
        sh[t] += u; __syncthreads();
    }
    if (i < n) offs[i] = sh[t] - v;
    if (t == 255) bsum[blockIdx.x] = sh[255];
}

// every block re-scans the (nb<=256) block sums in LDS, then adds its base
__global__ __launch_bounds__(256) void k_scanBC(int* offs, int* cursor, const int* __restrict__ bsum,
                                                int nb, int n) {
    __shared__ int sh[256];
    int t = threadIdx.x;
    int v = (t < nb) ? bsum[t] : 0;
    sh[t] = v; __syncthreads();
    #pragma unroll
    for (int off = 1; off < 256; off <<= 1) {
        int u = (t >= off) ? sh[t - off] : 0;
        __syncthreads();
        sh[t] += u; __syncthreads();
    }
    // sh[k] = inclusive sum through block k
    if (blockIdx.x == 0 && t == 0) { offs[n] = sh[nb - 1]; cursor[n] = sh[nb - 1]; }
    int base = (blockIdx.x > 0) ? sh[blockIdx.x - 1] : 0;
    __syncthreads();
    int i = blockIdx.x * 256 + t;
    if (i < n) {
        int o = offs[i] + base;
        offs[i] = o; cursor[i] = o;
    }
}

__global__ void k_fill(const int* __restrict__ ei, int E_in, int Etot, const int* flags,
                       int* cursor, int* s_src) {
    int e = blockIdx.x * blockDim.x + threadIdx.x;
    if (e >= Etot) return;
    int src, dst; edge_sd(ei, e, E_in, flags[1], src, dst);
    int p = atomicAdd(&cursor[dst], 1);
    s_src[p] = src;
}

// ---- fused dual MFMA GEMM with LDS-staged B (shared by the block's 4 waves) ----
// Yl/Yr[M,NOUT] = X[M,128] @ {WTl,WTr}. Per 64-col group: stage 2x64x128 bf16 tile
// in LDS (stride 136 -> <=2-way bank aliasing, free per m136), all waves consume.
// Tile = 2 sides x 64 rows x 16 bf16x8-vectors = 2048 vectors; 256 thr x 8 each.
#define BPAD 136
template <int NOUT>
__global__ __launch_bounds__(256) void k_gemm2(const ushort_t* __restrict__ X,
                                               const ushort_t* __restrict__ WTl,
                                               const ushort_t* __restrict__ WTr,
                                               ushort_t* __restrict__ Yl,
                                               ushort_t* __restrict__ Yr, int M) {
    __shared__ ushort_t smem[2 * 64 * BPAD];
    const int lane = threadIdx.x & 63, wid = threadIdx.x >> 6;
    const int rt = blockIdx.x * 4 + wid;
    const bool active = rt < (M >> 4);
    const int quad = lane >> 4, lo = lane & 15;

    bf16x8 afr[4];
    if (active) {
        const ushort_t* xrow = X + (size_t)(rt * 16 + lo) * 128 + quad * 8;
        #pragma unroll
        for (int kc = 0; kc < 4; kc++) afr[kc] = *(const bf16x8*)(xrow + kc * 32);
    }

    for (int g = 0; g < NOUT / 64; g++) {
        __syncthreads();
        // cooperative stage: 2048 vectors (2 sides x 64 rows x 16 vecs), 8 per thread
        #pragma unroll
        for (int i = 0; i < 8; i++) {
            int vecid = threadIdx.x * 8 + i;
            int side = vecid >> 10, row = (vecid >> 4) & 63, v = vecid & 15;
            const ushort_t* src = (side ? WTr : WTl) + (size_t)(g * 64 + row) * 128 + v * 8;
            *(bf16x8*)(smem + (size_t)(side * 64 + row) * BPAD + v * 8) = *(const bf16x8*)src;
        }
        __syncthreads();
        if (!active) continue;
        #pragma unroll
        for (int side = 0; side < 2; side++) {
            ushort_t* Y = side ? Yr : Yl;
            f32x4 acc[4];
            #pragma unroll
            for (int nt = 0; nt < 4; nt++) acc[nt] = (f32x4){0.f, 0.f, 0.f, 0.f};
            #pragma unroll
            for (int nt = 0; nt < 4; nt++) {
                const ushort_t* brow = smem + (size_t)(side * 64 + nt * 16 + lo) * BPAD + quad * 8;
                #pragma unroll
                for (int kc = 0; kc < 4; kc++) {
                    bf16x8 b = *(const bf16x8*)(brow + kc * 32);
                    acc[nt] = __builtin_amdgcn_mfma_f32_16x16x32_bf16(afr[kc], b, acc[nt], 0, 0, 0);
                }
            }
            // C/D: col = lane&15, row = quad*4 + reg  [m89-verified]
            #pragma unroll
            for (int nt = 0; nt < 4; nt++) {
                int col = g * 64 + nt * 16 + lo;
                #pragma unroll
                for (int ri = 0; ri < 4; ri++) {
                    int row = rt * 16 + quad * 4 + ri;
                    Y[(size_t)row * NOUT + col] = f2bf(acc[nt][ri]);
                }
            }
        }
    }
}

// ======== layer 1 FUSED: slot-parallel exp-sum gather -> h1 (bf16) ========
// wave per node. 4 slots x 16 lanes; lane covers 8 ch; head = (lane&15)>>2.
__global__ __launch_bounds__(256) void k_l1(const ushort_t* __restrict__ xl,
                                            const ushort_t* __restrict__ xr,
                                            const int* __restrict__ offs,
                                            const int* __restrict__ s_src,
                                            const float* __restrict__ att,
                                            const float* __restrict__ b1,
                                            int n, ushort_t* __restrict__ h1) {
    int lane = threadIdx.x & 63, wid = threadIdx.x >> 6;
    int node = blockIdx.x * 4 + wid;
    if (node >= n) return;
    int slot = lane >> 4, sub = lane & 15;
    int chb = sub * 8;

    uint4 xw = *(const uint4*)(xr + (size_t)node * 128 + chb);
    float2 xv[4] = {up2(xw.x), up2(xw.y), up2(xw.z), up2(xw.w)};
    float2 a6[4], a4[4];
    #pragma unroll
    for (int j = 0; j < 4; j++) {
        float2 a = make_float2(att[chb + 2 * j], att[chb + 2 * j + 1]);
        a6[j] = make_float2(0.6f * LOG2E * a.x, 0.6f * LOG2E * a.y);
        a4[j] = make_float2(0.4f * LOG2E * a.x, 0.4f * LOG2E * a.y);
    }

    int o0 = offs[node], o1 = offs[node + 1];
    float s = 0.f;
    float2 acc[4] = {{0.f,0.f},{0.f,0.f},{0.f,0.f},{0.f,0.f}};

    int i = o0 + slot;
    uint4 w;
    if (i < o1) w = *(const uint4*)(xl + (size_t)s_src[i] * 128 + chb);
    while (i < o1) {
        uint4 wc = w;
        int in = i + 4;
        if (in < o1) w = *(const uint4*)(xl + (size_t)s_src[in] * 128 + chb);
        float2 v[4] = {up2(wc.x), up2(wc.y), up2(wc.z), up2(wc.w)};
        float e = 0.f;
        #pragma unroll
        for (int j = 0; j < 4; j++)
            e = dot2(make_float2(v[j].x + xv[j].x, v[j].y + xv[j].y), a6[j], a4[j], e);
        e += __shfl_xor(e, 1, 64);
        e += __shfl_xor(e, 2, 64);          // reduce over 4-lane head group
        float p = __builtin_amdgcn_exp2f(fminf(e, 115.f));
        s += p;
        #pragma unroll
        for (int j = 0; j < 4; j++) {
            acc[j].x = fmaf(p, v[j].x, acc[j].x);
            acc[j].y = fmaf(p, v[j].y, acc[j].y);
        }
        i = in;
    }
    // merge the 4 slots: plain butterfly adds
    #pragma unroll
    for (int off = 16; off <= 32; off <<= 1) {
        s += __shfl_xor(s, off, 64);
        #pragma unroll
        for (int j = 0; j < 4; j++) {
            acc[j].x += __shfl_xor(acc[j].x, off, 64);
            acc[j].y += __shfl_xor(acc[j].y, off, 64);
        }
    }
    if (slot == 0) {
        float inv = 1.f / s;
        uint_t pk[4];
        #pragma unroll
        for (int j = 0; j < 4; j++) {
            float r0 = fmaxf(fmaf(acc[j].x, inv, b1[chb + 2 * j]),     0.f);
            float r1 = fmaxf(fmaf(acc[j].y, inv, b1[chb + 2 * j + 1]), 0.f);
            pk[j] = (uint_t)f2bf(r0) | ((uint_t)f2bf(r1) << 16);
        }
        *(uint4*)(h1 + (size_t)node * 128 + chb) = make_uint4(pk[0], pk[1], pk[2], pk[3]);
    }
}

// ======== layer 2 FUSED: slot-parallel exp-sum + mean-heads + b2 + decoder ========
// block per node; wave = head. 4 slots x 16 lanes x 8 ch.
__global__ __launch_bounds__(256) void k_l2(const ushort_t* __restrict__ xl,
                                            const ushort_t* __restrict__ xr,
                                            const int* __restrict__ offs,
                                            const int* __restrict__ s_src,
                                            const float* __restrict__ att,
                                            const float* __restrict__ b2,
                                            const float* __restrict__ Wo,
                                            const float* __restrict__ bo,
                                            int n, const int* flags, void* dout) {
    __shared__ float part[4][128];
    __shared__ float hbuf[128];
    int node = blockIdx.x;
    int h = threadIdx.x >> 6, lane = threadIdx.x & 63;
    int slot = lane >> 4, sub = lane & 15;
    int chb = sub * 8;
    size_t choff = (size_t)h * 128 + chb;

    uint4 xw = *(const uint4*)(xr + (size_t)node * 512 + choff);
    float2 xv[4] = {up2(xw.x), up2(xw.y), up2(xw.z), up2(xw.w)};
    float2 a6[4], a4[4];
    #pragma unroll
    for (int j = 0; j < 4; j++) {
        float2 a = make_float2(att[choff + 2 * j], att[choff + 2 * j + 1]);
        a6[j] = make_float2(0.6f * LOG2E * a.x, 0.6f * LOG2E * a.y);
        a4[j] = make_float2(0.4f * LOG2E * a.x, 0.4f * LOG2E * a.y);
    }

    int o0 = offs[node], o1 = offs[node + 1];
    float s = 0.f;
    float2 acc[4] = {{0.f,0.f},{0.f,0.f},{0.f,0.f},{0.f,0.f}};

    int i = o0 + slot;
    uint4 w;
    if (i < o1) w = *(const uint4*)(xl + (size_t)s_src[i] * 512 + choff);
    while (i < o1) {
        uint4 wc = w;
        int in = i + 4;
        if (in < o1) w = *(const uint4*)(xl + (size_t)s_src[in] * 512 + choff);
        float2 v[4] = {up2(wc.x), up2(wc.y), up2(wc.z), up2(wc.w)};
        float e = 0.f;
        #pragma unroll
        for (int j = 0; j < 4; j++)
            e = dot2(make_float2(v[j].x + xv[j].x, v[j].y + xv[j].y), a6[j], a4[j], e);
        #pragma unroll
        for (int o = 1; o < 16; o <<= 1) e += __shfl_xor(e, o, 64);  // 16-lane slot reduce
        float p = __builtin_amdgcn_exp2f(fminf(e, 115.f));
        s += p;
        #pragma unroll
        for (int j = 0; j < 4; j++) {
            acc[j].x = fmaf(p, v[j].x, acc[j].x);
            acc[j].y = fmaf(p, v[j].y, acc[j].y);
        }
        i = in;
    }
    // merge slots: plain butterfly adds
    #pragma unroll
    for (int off = 16; off <= 32; off <<= 1) {
        s += __shfl_xor(s, off, 64);
        #pragma unroll
        for (int j = 0; j < 4; j++) {
            acc[j].x += __shfl_xor(acc[j].x, off, 64);
            acc[j].y += __shfl_xor(acc[j].y, off, 64);
        }
    }
    if (slot == 0) {
        float inv = 1.f / s;
        #pragma unroll
        for (int j = 0; j < 4; j++) {
            part[h][chb + 2 * j]     = acc[j].x * inv;
            part[h][chb + 2 * j + 1] = acc[j].y * inv;
        }
    }
    __syncthreads();
    int t = threadIdx.x;
    int bf = flags[0];
    if (t < 128) {
        float hm = 0.25f * (part[0][t] + part[1][t] + part[2][t] + part[3][t]) + b2[t];
        hbuf[t] = hm;
        size_t oidx = (size_t)n * 2 + (size_t)node * 128 + t;
        if (bf) ((ushort_t*)dout)[oidx] = f2bf(hm);
        else    ((float*)dout)[oidx]    = hm;
    }
    __syncthreads();
    if (h < 2) {  // decoder
        float v = hbuf[lane] * Wo[lane * 2 + h] + hbuf[lane + 64] * Wo[(lane + 64) * 2 + h];
        #pragma unroll
        for (int o = 32; o > 0; o >>= 1) v += __shfl_xor(v, o, 64);
        if (lane == 0) {
            float r = v + bo[h];
            size_t oidx = (size_t)node * 2 + h;
            if (bf) ((ushort_t*)dout)[oidx] = f2bf(r);
            else    ((float*)dout)[oidx]    = r;
        }
    }
}

extern "C" void kernel_launch(void* const* d_in, const int* in_sizes, int n_in,
                              void* d_out, int out_size, void* d_ws, size_t ws_size,
                              hipStream_t stream) {
    const void* x    = d_in[0];
    const int*  ei   = (const int*)d_in[1];
    const void* Wl1  = d_in[2];
    const void* Wr1  = d_in[3];
    const void* att1 = d_in[4];
    const void* b1   = d_in[5];
    const void* Wl2  = d_in[6];
    const void* Wr2  = d_in[7];
    const void* att2 = d_in[8];
    const void* b2   = d_in[9];
    const void* Wo   = d_in[10];
    const void* bo   = d_in[11];

    const int N    = in_sizes[0] / 128;   // 50000
    const int E_in = in_sizes[1] / 2;     // 800000
    const int Etot = E_in + N;

    const int sW1 = in_sizes[2], sW2 = in_sizes[6];
    const int satt1 = in_sizes[4], sb1 = in_sizes[5];
    const int satt2 = in_sizes[8], sb2 = in_sizes[9];
    const int sWo = in_sizes[10], sbo = in_sizes[11];

    char* w = (char*)d_ws;
    size_t off = 0;
    auto take = [&](size_t bytes) -> void* {
        void* p = w + off;
        off += (bytes + 255) & ~(size_t)255;
        return p;
    };
    int*      flags  = (int*)take(256);
    ushort_t* xb     = (ushort_t*)take((size_t)N * 128 * sizeof(ushort_t));
    ushort_t* WTl1   = (ushort_t*)take((size_t)sW1 * 2);
    ushort_t* WTr1   = (ushort_t*)take((size_t)sW1 * 2);
    ushort_t* WTl2   = (ushort_t*)take((size_t)sW2 * 2);
    ushort_t* WTr2   = (ushort_t*)take((size_t)sW2 * 2);
    float*    att1f  = (float*)take((size_t)satt1 * 4);
    float*    b1f    = (float*)take((size_t)sb1 * 4);
    float*    att2f  = (float*)take((size_t)satt2 * 4);
    float*    b2f    = (float*)take((size_t)sb2 * 4);
    float*    Wof    = (float*)take((size_t)sWo * 4);
    float*    bof    = (float*)take((size_t)sbo * 4);
    int*      deg    = (int*)take((size_t)N * sizeof(int));
    int*      offs   = (int*)take((size_t)(N + 1) * sizeof(int));
    int*      cursor = (int*)take((size_t)(N + 1) * sizeof(int));
    int*      bsum   = (int*)take(1024);
    int*      s_src  = (int*)take((size_t)Etot * sizeof(int));
    ushort_t* h1     = (ushort_t*)take((size_t)N * 128 * sizeof(ushort_t));
    ushort_t* xl1b   = (ushort_t*)take((size_t)N * 128 * sizeof(ushort_t));
    ushort_t* xr1b   = (ushort_t*)take((size_t)N * 128 * sizeof(ushort_t));
    ushort_t* xl2b   = (ushort_t*)take((size_t)N * 512 * sizeof(ushort_t));
    ushort_t* xr2b   = (ushort_t*)take((size_t)N * 512 * sizeof(ushort_t));

    dim3 b256(256);
    const int nb = (N + 255) / 256;       // 196 scan blocks

    k_detect<<<1, b256, 0, stream>>>((const uint_t*)x, ei, flags);
    hipMemsetAsync(deg, 0, (size_t)N * sizeof(int), stream);

    long prep_total = (long)Etot + (long)N * 128 + 2L * sW1 + 2L * sW2
                    + satt1 + sb1 + satt2 + sb2 + sWo + sbo;
    int prep_blocks = (int)((prep_total + 255) / 256);
    k_prep<<<prep_blocks, b256, 0, stream>>>(x, Wl1, Wr1, att1, b1, Wl2, Wr2, att2, b2, Wo, bo,
                                             ei, E_in, Etot, deg, xb, WTl1, WTr1, WTl2, WTr2,
                                             att1f, b1f, att2f, b2f, Wof, bof,
                                             N, sW1, sW2, satt1, sb1, satt2, sb2, sWo, sbo, flags);

    k_scanA<<<nb, b256, 0, stream>>>(deg, offs, bsum, N);
    k_scanBC<<<nb, b256, 0, stream>>>(offs, cursor, bsum, nb, N);
    k_fill<<<(Etot + 255) / 256, b256, 0, stream>>>(ei, E_in, Etot, flags, cursor, s_src);

    dim3 gg((N / 16 + 3) / 4);
    k_gemm2<128><<<gg, b256, 0, stream>>>(xb, WTl1, WTr1, xl1b, xr1b, N);
    k_l1<<<(N + 3) / 4, b256, 0, stream>>>(xl1b, xr1b, offs, s_src, att1f, b1f, N, h1);

    k_gemm2<512><<<gg, b256, 0, stream>>>(h1, WTl2, WTr2, xl2b, xr2b, N);

    k_l2<<<N, b256, 0, stream>>>(xl2b, xr2b, offs, s_src, att2f, b2f, Wof, bof, N, flags, d_out);
}

// Round 10
// 452.589 us; speedup vs baseline: 1.3187x; 1.0229x over previous
//
#include <hip/hip_runtime.h>

#define NEG_SLOPE 0.2f
#define LOG2E 1.44269504088896340736f

typedef unsigned short ushort_t;
typedef unsigned int uint_t;
typedef __attribute__((ext_vector_type(8))) short bf16x8;   // 8 bf16 in 4 VGPRs
typedef __attribute__((ext_vector_type(4))) float f32x4;
typedef __attribute__((ext_vector_type(2))) float f32x2;    // maps to v_pk_*_f32 on gfx950

__device__ inline float bf2f(ushort_t u) { union { uint_t i; float f; } v; v.i = ((uint_t)u) << 16; return v.f; }
__device__ inline ushort_t f2bf(float f) {
    union { float f; uint_t u; } v; v.f = f;
    uint_t r = v.u + 0x7fffu + ((v.u >> 16) & 1u);
    return (ushort_t)(r >> 16);
}
__device__ inline float2 up2(uint_t w) { return make_float2(bf2f((ushort_t)(w & 0xFFFFu)), bf2f((ushort_t)(w >> 16))); }
// unpack 2 packed bf16 -> f32x2 (2 ops: shl, and)
__device__ inline f32x2 up2v(uint_t w) {
    union { uint_t i; float f; } lo, hi;
    lo.i = w << 16; hi.i = w & 0xFFFF0000u;
    return (f32x2){lo.f, hi.f};
}
// dtype-flexible loads (bf=1: buffer holds bf16; bf=0: fp32)
__device__ inline float ld_f(const void* p, size_t i, int bf) { return bf ? bf2f(((const ushort_t*)p)[i]) : ((const float*)p)[i]; }
__device__ inline ushort_t ld_b(const void* p, size_t i, int bf) { return bf ? ((const ushort_t*)p)[i] : f2bf(((const float*)p)[i]); }
// edge fetch with int64/int32 handling; self-loops appended at e >= E_in
__device__ inline void edge_sd(const int* __restrict__ ei, int e, int E_in, int i64, int& src, int& dst) {
    if (e < E_in) {
        if (i64) { src = ei[2 * (size_t)e]; dst = ei[2 * ((size_t)E_in + e)]; }
        else     { src = ei[e];             dst = ei[(size_t)E_in + e]; }
    } else { src = dst = e - E_in; }
}

// ---------------- dtype detection ----------------
__global__ void k_detect(const uint_t* __restrict__ xw, const int* __restrict__ ei, int* flags) {
    __shared__ int cnt;
    if (threadIdx.x == 0) cnt = 0;
    __syncthreads();
    uint_t w = xw[threadIdx.x];
    int eb = (int)((w >> 7) & 0xFFu);
    if (eb >= 113 && eb <= 142) atomicAdd(&cnt, 1);
    __syncthreads();
    if (threadIdx.x == 0) {
        flags[0] = (cnt > 128) ? 1 : 0;
        int z = 0;
        #pragma unroll
        for (int i = 1; i < 16; i += 2) z += (ei[i] == 0) ? 1 : 0;
        flags[1] = (z == 8) ? 1 : 0;
    }
}

// ------ fused front-end: degree count | cvt x->bf16 | build WT | small fp32 params ------
// deg must be pre-zeroed (hipMemsetAsync before this kernel).
__global__ __launch_bounds__(256) void k_prep(const void* __restrict__ x, const void* Wl1, const void* Wr1,
                      const void* att1, const void* b1, const void* Wl2, const void* Wr2,
                      const void* att2, const void* b2, const void* Wo, const void* bo,
                      const int* __restrict__ ei, int E_in, int Etot, int* deg, ushort_t* xb,
                      ushort_t* WTl1, ushort_t* WTr1, ushort_t* WTl2, ushort_t* WTr2,
                      float* att1f, float* b1f, float* att2f, float* b2f, float* Wof, float* bof,
                      int N, int sW1, int sW2, int satt1, int sb1, int satt2, int sb2, int sWo, int sbo,
                      const int* flags) {
    int bf = flags[0];
    long r = (long)blockIdx.x * 256 + threadIdx.x;
    if (r < Etot) {   // degree count
        int e = (int)r, dst;
        if (e < E_in) dst = flags[1] ? ei[2 * ((size_t)E_in + e)] : ei[(size_t)E_in + e];
        else          dst = e - E_in;
        atomicAdd(&deg[dst], 1);
        return;
    }
    r -= Etot;
    long nx = (long)N * 128;
    if (r < nx) { xb[r] = ld_b(x, r, bf); return; }          r -= nx;
    if (r < sW1) { int n = r >> 7, k = r & 127; WTl1[r] = ld_b(Wl1, (size_t)k * 128 + n, bf); return; } r -= sW1;
    if (r < sW1) { int n = r >> 7, k = r & 127; WTr1[r] = ld_b(Wr1, (size_t)k * 128 + n, bf); return; } r -= sW1;
    if (r < sW2) { int n = r >> 7, k = r & 127; WTl2[r] = ld_b(Wl2, (size_t)k * 512 + n, bf); return; } r -= sW2;
    if (r < sW2) { int n = r >> 7, k = r & 127; WTr2[r] = ld_b(Wr2, (size_t)k * 512 + n, bf); return; } r -= sW2;
    if (r < satt1) { att1f[r] = ld_f(att1, r, bf); return; } r -= satt1;
    if (r < sb1)   { b1f[r]   = ld_f(b1, r, bf);   return; } r -= sb1;
    if (r < satt2) { att2f[r] = ld_f(att2, r, bf); return; } r -= satt2;
    if (r < sb2)   { b2f[r]   = ld_f(b2, r, bf);   return; } r -= sb2;
    if (r < sWo)   { Wof[r]   = ld_f(Wo, r, bf);   return; } r -= sWo;
    if (r < sbo)   { bof[r]   = ld_f(bo, r, bf);   return; }
}

// -------- hierarchical exclusive scan: A (block scan) -> BC (re-scan sums + add) --------
__global__ __launch_bounds__(256) void k_scanA(const int* __restrict__ deg, int* offs, int* bsum, int n) {
    __shared__ int sh[256];
    int t = threadIdx.x;
    int i = blockIdx.x * 256 + t;
    int v = (i < n) ? deg[i] : 0;
    sh[t] = v; __syncthreads();
    #pragma unroll
    for (int off = 1; off < 256; off <<= 1) {
        int u = (t >= off) ? sh[t - off] : 0;
        __syncthreads();
        sh[t] += u; __syncthreads();
    }
    if (i < n) offs[i] = sh[t] - v;
    if (t == 255) bsum[blockIdx.x] = sh[255];
}

// every block re-scans the (nb<=256) block sums in LDS, then adds its base
__global__ __launch_bounds__(256) void k_scanBC(int* offs, int* cursor, const int* __restrict__ bsum,
                                                int nb, int n) {
    __shared__ int sh[256];
    int t = threadIdx.x;
    int v = (t < nb) ? bsum[t] : 0;
    sh[t] = v; __syncthreads();
    #pragma unroll
    for (int off = 1; off < 256; off <<= 1) {
        int u = (t >= off) ? sh[t - off] : 0;
        __syncthreads();
        sh[t] += u; __syncthreads();
    }
    if (blockIdx.x == 0 && t == 0) { offs[n] = sh[nb - 1]; cursor[n] = sh[nb - 1]; }
    int base = (blockIdx.x > 0) ? sh[blockIdx.x - 1] : 0;
    __syncthreads();
    int i = blockIdx.x * 256 + t;
    if (i < n) {
        int o = offs[i] + base;
        offs[i] = o; cursor[i] = o;
    }
}

__global__ void k_fill(const int* __restrict__ ei, int E_in, int Etot, const int* flags,
                       int* cursor, int* s_src) {
    int e = blockIdx.x * blockDim.x + threadIdx.x;
    if (e >= Etot) return;
    int src, dst; edge_sd(ei, e, E_in, flags[1], src, dst);
    int p = atomicAdd(&cursor[dst], 1);
    s_src[p] = src;
}

// ---- fused dual MFMA GEMM with LDS-staged B (shared by the block's 4 waves) ----
#define BPAD 136
template <int NOUT>
__global__ __launch_bounds__(256) void k_gemm2(const ushort_t* __restrict__ X,
                                               const ushort_t* __restrict__ WTl,
                                               const ushort_t* __restrict__ WTr,
                                               ushort_t* __restrict__ Yl,
                                               ushort_t* __restrict__ Yr, int M) {
    __shared__ ushort_t smem[2 * 64 * BPAD];
    const int lane = threadIdx.x & 63, wid = threadIdx.x >> 6;
    const int rt = blockIdx.x * 4 + wid;
    const bool active = rt < (M >> 4);
    const int quad = lane >> 4, lo = lane & 15;

    bf16x8 afr[4];
    if (active) {
        const ushort_t* xrow = X + (size_t)(rt * 16 + lo) * 128 + quad * 8;
        #pragma unroll
        for (int kc = 0; kc < 4; kc++) afr[kc] = *(const bf16x8*)(xrow + kc * 32);
    }

    for (int g = 0; g < NOUT / 64; g++) {
        __syncthreads();
        // cooperative stage: 2048 vectors (2 sides x 64 rows x 16 vecs), 8 per thread
        #pragma unroll
        for (int i = 0; i < 8; i++) {
            int vecid = threadIdx.x * 8 + i;
            int side = vecid >> 10, row = (vecid >> 4) & 63, v = vecid & 15;
            const ushort_t* src = (side ? WTr : WTl) + (size_t)(g * 64 + row) * 128 + v * 8;
            *(bf16x8*)(smem + (size_t)(side * 64 + row) * BPAD + v * 8) = *(const bf16x8*)src;
        }
        __syncthreads();
        if (!active) continue;
        #pragma unroll
        for (int side = 0; side < 2; side++) {
            ushort_t* Y = side ? Yr : Yl;
            f32x4 acc[4];
            #pragma unroll
            for (int nt = 0; nt < 4; nt++) acc[nt] = (f32x4){0.f, 0.f, 0.f, 0.f};
            #pragma unroll
            for (int nt = 0; nt < 4; nt++) {
                const ushort_t* brow = smem + (size_t)(side * 64 + nt * 16 + lo) * BPAD + quad * 8;
                #pragma unroll
                for (int kc = 0; kc < 4; kc++) {
                    bf16x8 b = *(const bf16x8*)(brow + kc * 32);
                    acc[nt] = __builtin_amdgcn_mfma_f32_16x16x32_bf16(afr[kc], b, acc[nt], 0, 0, 0);
                }
            }
            // C/D: col = lane&15, row = quad*4 + reg  [m89-verified]
            #pragma unroll
            for (int nt = 0; nt < 4; nt++) {
                int col = g * 64 + nt * 16 + lo;
                #pragma unroll
                for (int ri = 0; ri < 4; ri++) {
                    int row = rt * 16 + quad * 4 + ri;
                    Y[(size_t)row * NOUT + col] = f2bf(acc[nt][ri]);
                }
            }
        }
    }
}

// ======== layer 1 FUSED: slot-parallel exp-sum gather -> h1 (bf16), packed-fp32 ========
// wave per node. 4 slots x 16 lanes; lane covers 8 ch; head = (lane&15)>>2.
// leaky(m) = max(m, 0.2m); att pre-scaled by log2e; v_pk_*_f32 via f32x2.
__global__ __launch_bounds__(256) void k_l1(const ushort_t* __restrict__ xl,
                                            const ushort_t* __restrict__ xr,
                                            const int* __restrict__ offs,
                                            const int* __restrict__ s_src,
                                            const float* __restrict__ att,
                                            const float* __restrict__ b1,
                                            int n, ushort_t* __restrict__ h1) {
    int lane = threadIdx.x & 63, wid = threadIdx.x >> 6;
    int node = blockIdx.x * 4 + wid;
    if (node >= n) return;
    int slot = lane >> 4, sub = lane & 15;
    int chb = sub * 8;

    uint4 xw = *(const uint4*)(xr + (size_t)node * 128 + chb);
    f32x2 xv[4] = {up2v(xw.x), up2v(xw.y), up2v(xw.z), up2v(xw.w)};
    f32x2 aL[4];
    #pragma unroll
    for (int j = 0; j < 4; j++) {
        f32x2 a = {att[chb + 2 * j], att[chb + 2 * j + 1]};
        aL[j] = a * (float)LOG2E;
    }

    int o0 = offs[node], o1 = offs[node + 1];
    float s = 0.f;
    f32x2 acc[4] = {{0.f,0.f},{0.f,0.f},{0.f,0.f},{0.f,0.f}};

    int i = o0 + slot;
    uint4 w;
    if (i < o1) w = *(const uint4*)(xl + (size_t)s_src[i] * 128 + chb);
    while (i < o1) {
        uint4 wc = w;
        int in = i + 4;
        if (in < o1) w = *(const uint4*)(xl + (size_t)s_src[in] * 128 + chb);
        f32x2 v[4] = {up2v(wc.x), up2v(wc.y), up2v(wc.z), up2v(wc.w)};
        f32x2 es = {0.f, 0.f};
        #pragma unroll
        for (int j = 0; j < 4; j++) {
            f32x2 m = v[j] + xv[j];
            f32x2 l = __builtin_elementwise_max(m, m * NEG_SLOPE);
            es = __builtin_elementwise_fma(aL[j], l, es);
        }
        float e = es.x + es.y;
        e += __shfl_xor(e, 1, 64);
        e += __shfl_xor(e, 2, 64);          // reduce over 4-lane head group
        float p = __builtin_amdgcn_exp2f(fminf(e, 115.f));
        s += p;
        f32x2 pp = {p, p};
        #pragma unroll
        for (int j = 0; j < 4; j++)
            acc[j] = __builtin_elementwise_fma(pp, v[j], acc[j]);
        i = in;
    }
    // merge the 4 slots: plain butterfly adds
    #pragma unroll
    for (int off = 16; off <= 32; off <<= 1) {
        s += __shfl_xor(s, off, 64);
        #pragma unroll
        for (int j = 0; j < 4; j++) {
            f32x2 o = {__shfl_xor(acc[j].x, off, 64), __shfl_xor(acc[j].y, off, 64)};
            acc[j] += o;
        }
    }
    if (slot == 0) {
        float inv = 1.f / s;
        uint_t pk[4];
        #pragma unroll
        for (int j = 0; j < 4; j++) {
            float r0 = fmaxf(fmaf(acc[j].x, inv, b1[chb + 2 * j]),     0.f);
            float r1 = fmaxf(fmaf(acc[j].y, inv, b1[chb + 2 * j + 1]), 0.f);
            pk[j] = (uint_t)f2bf(r0) | ((uint_t)f2bf(r1) << 16);
        }
        *(uint4*)(h1 + (size_t)node * 128 + chb) = make_uint4(pk[0], pk[1], pk[2], pk[3]);
    }
}

// ======== layer 2 FUSED: slot-parallel exp-sum + mean-heads + b2 + decoder, packed-fp32 ========
// block per node; wave = head. 4 slots x 16 lanes x 8 ch.
__global__ __launch_bounds__(256) void k_l2(const ushort_t* __restrict__ xl,
                                            const ushort_t* __restrict__ xr,
                                            const int* __restrict__ offs,
                                            const int* __restrict__ s_src,
                                            const float* __restrict__ att,
                                            const float* __restrict__ b2,
                                            const float* __restrict__ Wo,
                                            const float* __restrict__ bo,
                                            int n, const int* flags, void* dout) {
    __shared__ float part[4][128];
    __shared__ float hbuf[128];
    int node = blockIdx.x;
    int h = threadIdx.x >> 6, lane = threadIdx.x & 63;
    int slot = lane >> 4, sub = lane & 15;
    int chb = sub * 8;
    size_t choff = (size_t)h * 128 + chb;

    uint4 xw = *(const uint4*)(xr + (size_t)node * 512 + choff);
    f32x2 xv[4] = {up2v(xw.x), up2v(xw.y), up2v(xw.z), up2v(xw.w)};
    f32x2 aL[4];
    #pragma unroll
    for (int j = 0; j < 4; j++) {
        f32x2 a = {att[choff + 2 * j], att[choff + 2 * j + 1]};
        aL[j] = a * (float)LOG2E;
    }

    int o0 = offs[node], o1 = offs[node + 1];
    float s = 0.f;
    f32x2 acc[4] = {{0.f,0.f},{0.f,0.f},{0.f,0.f},{0.f,0.f}};

    int i = o0 + slot;
    uint4 w;
    if (i < o1) w = *(const uint4*)(xl + (size_t)s_src[i] * 512 + choff);
    while (i < o1) {
        uint4 wc = w;
        int in = i + 4;
        if (in < o1) w = *(const uint4*)(xl + (size_t)s_src[in] * 512 + choff);
        f32x2 v[4] = {up2v(wc.x), up2v(wc.y), up2v(wc.z), up2v(wc.w)};
        f32x2 es = {0.f, 0.f};
        #pragma unroll
        for (int j = 0; j < 4; j++) {
            f32x2 m = v[j] + xv[j];
            f32x2 l = __builtin_elementwise_max(m, m * NEG_SLOPE);
            es = __builtin_elementwise_fma(aL[j], l, es);
        }
        float e = es.x + es.y;
        #pragma unroll
        for (int o = 1; o < 16; o <<= 1) e += __shfl_xor(e, o, 64);  // 16-lane slot reduce
        float p = __builtin_amdgcn_exp2f(fminf(e, 115.f));
        s += p;
        f32x2 pp = {p, p};
        #pragma unroll
        for (int j = 0; j < 4; j++)
            acc[j] = __builtin_elementwise_fma(pp, v[j], acc[j]);
        i = in;
    }
    // merge slots: plain butterfly adds
    #pragma unroll
    for (int off = 16; off <= 32; off <<= 1) {
        s += __shfl_xor(s, off, 64);
        #pragma unroll
        for (int j = 0; j < 4; j++) {
            f32x2 o = {__shfl_xor(acc[j].x, off, 64), __shfl_xor(acc[j].y, off, 64)};
            acc[j] += o;
        }
    }
    if (slot == 0) {
        float inv = 1.f / s;
        #pragma unroll
        for (int j = 0; j < 4; j++) {
            part[h][chb + 2 * j]     = acc[j].x * inv;
            part[h][chb + 2 * j + 1] = acc[j].y * inv;
        }
    }
    __syncthreads();
    int t = threadIdx.x;
    int bf = flags[0];
    if (t < 128) {
        float hm = 0.25f * (part[0][t] + part[1][t] + part[2][t] + part[3][t]) + b2[t];
        hbuf[t] = hm;
        size_t oidx = (size_t)n * 2 + (size_t)node * 128 + t;
        if (bf) ((ushort_t*)dout)[oidx] = f2bf(hm);
        else    ((float*)dout)[oidx]    = hm;
    }
    __syncthreads();
    if (h < 2) {  // decoder
        float v = hbuf[lane] * Wo[lane * 2 + h] + hbuf[lane + 64] * Wo[(lane + 64) * 2 + h];
        #pragma unroll
        for (int o = 32; o > 0; o >>= 1) v += __shfl_xor(v, o, 64);
        if (lane == 0) {
            float r = v + bo[h];
            size_t oidx = (size_t)node * 2 + h;
            if (bf) ((ushort_t*)dout)[oidx] = f2bf(r);
            else    ((float*)dout)[oidx]    = r;
        }
    }
}

extern "C" void kernel_launch(void* const* d_in, const int* in_sizes, int n_in,
                              void* d_out, int out_size, void* d_ws, size_t ws_size,
                              hipStream_t stream) {
    const void* x    = d_in[0];
    const int*  ei   = (const int*)d_in[1];
    const void* Wl1  = d_in[2];
    const void* Wr1  = d_in[3];
    const void* att1 = d_in[4];
    const void* b1   = d_in[5];
    const void* Wl2  = d_in[6];
    const void* Wr2  = d_in[7];
    const void* att2 = d_in[8];
    const void* b2   = d_in[9];
    const void* Wo   = d_in[10];
    const void* bo   = d_in[11];

    const int N    = in_sizes[0] / 128;   // 50000
    const int E_in = in_sizes[1] / 2;     // 800000
    const int Etot = E_in + N;

    const int sW1 = in_sizes[2], sW2 = in_sizes[6];
    const int satt1 = in_sizes[4], sb1 = in_sizes[5];
    const int satt2 = in_sizes[8], sb2 = in_sizes[9];
    const int sWo = in_sizes[10], sbo = in_sizes[11];

    char* w = (char*)d_ws;
    size_t off = 0;
    auto take = [&](size_t bytes) -> void* {
        void* p = w + off;
        off += (bytes + 255) & ~(size_t)255;
        return p;
    };
    int*      flags  = (int*)take(256);
    ushort_t* xb     = (ushort_t*)take((size_t)N * 128 * sizeof(ushort_t));
    ushort_t* WTl1   = (ushort_t*)take((size_t)sW1 * 2);
    ushort_t* WTr1   = (ushort_t*)take((size_t)sW1 * 2);
    ushort_t* WTl2   = (ushort_t*)take((size_t)sW2 * 2);
    ushort_t* WTr2   = (ushort_t*)take((size_t)sW2 * 2);
    float*    att1f  = (float*)take((size_t)satt1 * 4);
    float*    b1f    = (float*)take((size_t)sb1 * 4);
    float*    att2f  = (float*)take((size_t)satt2 * 4);
    float*    b2f    = (float*)take((size_t)sb2 * 4);
    float*    Wof    = (float*)take((size_t)sWo * 4);
    float*    bof    = (float*)take((size_t)sbo * 4);
    int*      deg    = (int*)take((size_t)N * sizeof(int));
    int*      offs   = (int*)take((size_t)(N + 1) * sizeof(int));
    int*      cursor = (int*)take((size_t)(N + 1) * sizeof(int));
    int*      bsum   = (int*)take(1024);
    int*      s_src  = (int*)take((size_t)Etot * sizeof(int));
    ushort_t* h1     = (ushort_t*)take((size_t)N * 128 * sizeof(ushort_t));
    ushort_t* xl1b   = (ushort_t*)take((size_t)N * 128 * sizeof(ushort_t));
    ushort_t* xr1b   = (ushort_t*)take((size_t)N * 128 * sizeof(ushort_t));
    ushort_t* xl2b   = (ushort_t*)take((size_t)N * 512 * sizeof(ushort_t));
    ushort_t* xr2b   = (ushort_t*)take((size_t)N * 512 * sizeof(ushort_t));

    dim3 b256(256);
    const int nb = (N + 255) / 256;       // 196 scan blocks

    k_detect<<<1, b256, 0, stream>>>((const uint_t*)x, ei, flags);
    hipMemsetAsync(deg, 0, (size_t)N * sizeof(int), stream);

    long prep_total = (long)Etot + (long)N * 128 + 2L * sW1 + 2L * sW2
                    + satt1 + sb1 + satt2 + sb2 + sWo + sbo;
    int prep_blocks = (int)((prep_total + 255) / 256);
    k_prep<<<prep_blocks, b256, 0, stream>>>(x, Wl1, Wr1, att1, b1, Wl2, Wr2, att2, b2, Wo, bo,
                                             ei, E_in, Etot, deg, xb, WTl1, WTr1, WTl2, WTr2,
                                             att1f, b1f, att2f, b2f, Wof, bof,
                                             N, sW1, sW2, satt1, sb1, satt2, sb2, sWo, sbo, flags);

    k_scanA<<<nb, b256, 0, stream>>>(deg, offs, bsum, N);
    k_scanBC<<<nb, b256, 0, stream>>>(offs, cursor, bsum, nb, N);
    k_fill<<<(Etot + 255) / 256, b256, 0, stream>>>(ei, E_in, Etot, flags, cursor, s_src);

    dim3 gg((N / 16 + 3) / 4);
    k_gemm2<128><<<gg, b256, 0, stream>>>(xb, WTl1, WTr1, xl1b, xr1b, N);
    k_l1<<<(N + 3) / 4, b256, 0, stream>>>(xl1b, xr1b, offs, s_src, att1f, b1f, N, h1);

    k_gemm2<512><<<gg, b256, 0, stream>>>(h1, WTl2, WTr2, xl2b, xr2b, N);

    k_l2<<<N, b256, 0, stream>>>(xl2b, xr2b, offs, s_src, att2f, b2f, Wof, bof, N, flags, d_out);
}